// Round 3
// baseline (407.964 us; speedup 1.0000x reference)
//
#include <hip/hip_runtime.h>

#define TX 64
#define TY 20
#define PROWS (TY + 10)            // 30 rows of h-blurred data per tile
#define HSTR 68                    // 68*4=272 B rows -> every (row,xs mult 8) is 16B-aligned
#define IMW 512
#define IMH 512
#define NPLANES 96                 // 32 * 3
#define NBX (IMW / TX)             // 8
#define NBY ((IMH + TY - 1) / TY)  // 26 (last tile covers 12 valid rows)
#define NBLOCKS (NBX * NBY * NPLANES)  // 19968

// Gaussian(sigma=1.5, ws=11) weights, computed in double, rounded to fp32.
// Matches the fp32 reference to ~1e-8 abs (threshold is 7.1e-5).
__device__ __constant__ float GW[11] = {
    0.00102838f, 0.00759877f, 0.03600077f, 0.10936069f, 0.21300553f,
    0.26601172f,
    0.21300553f, 0.10936069f, 0.03600077f, 0.00759877f, 0.00102838f};

__global__ __launch_bounds__(256, 4) void ssim_main(
    const float* __restrict__ gen, const float* __restrict__ ref,
    double* __restrict__ acc) {
  __shared__ __align__(16) float sh[5][PROWS][HSTR];  // 40,800 B

  const int tid = threadIdx.x;
  const int bid = blockIdx.x;
  const int rem = bid % (NBX * NBY);
  const int plane = bid / (NBX * NBY);
  const int bx = rem % NBX;
  const int by = rem / NBX;
  const int x0 = bx * TX;
  const int y0 = by * TY;
  const float* gp = gen + (size_t)plane * (IMW * IMH);
  const float* rp = ref + (size_t)plane * (IMW * IMH);

  // ---- Phase 1: horizontal 11-tap blur of 5 quantities, read from GLOBAL.
  // 240 threads: (row 0..29) x (8 runs of 8 outputs). Window = 24 floats
  // loaded as 6 aligned float4 (whole-vec in/out of image; IMW%4==0).
  if (tid < PROWS * 8) {
    const int row = tid >> 3;
    const int xs = (tid & 7) * 8;
    const int gy = y0 - 5 + row;
    const bool rowok = (gy >= 0) && (gy < IMH);
    const int xbase = x0 + xs - 8;  // window cols [xbase, xbase+24)
    const float* grow = gp + (size_t)gy * IMW;
    const float* rrow = rp + (size_t)gy * IMW;

    float ga[24], ra[24];
#pragma unroll
    for (int k = 0; k < 6; ++k) {
      const int c = xbase + 4 * k;
      const bool ok = rowok && (c >= 0) && (c < IMW);
      float4 vg = make_float4(0.f, 0.f, 0.f, 0.f);
      float4 vr = make_float4(0.f, 0.f, 0.f, 0.f);
      if (ok) {
        float4 g4 = *(const float4*)(grow + c);
        float4 r4 = *(const float4*)(rrow + c);
        vg.x = fmaf(0.5f, g4.x, 0.5f); vg.y = fmaf(0.5f, g4.y, 0.5f);
        vg.z = fmaf(0.5f, g4.z, 0.5f); vg.w = fmaf(0.5f, g4.w, 0.5f);
        vr.x = fmaf(0.5f, r4.x, 0.5f); vr.y = fmaf(0.5f, r4.y, 0.5f);
        vr.z = fmaf(0.5f, r4.z, 0.5f); vr.w = fmaf(0.5f, r4.w, 0.5f);
      }
      ga[4 * k + 0] = vg.x; ga[4 * k + 1] = vg.y;
      ga[4 * k + 2] = vg.z; ga[4 * k + 3] = vg.w;
      ra[4 * k + 0] = vr.x; ra[4 * k + 1] = vr.y;
      ra[4 * k + 2] = vr.z; ra[4 * k + 3] = vr.w;
    }

    float acc5[5][8];
#pragma unroll
    for (int q = 0; q < 5; ++q)
#pragma unroll
      for (int o = 0; o < 8; ++o) acc5[q][o] = 0.f;

#pragma unroll
    for (int p = 0; p < 18; ++p) {   // window position; col = X-5+p = ga[p+3]
      const float g = ga[p + 3];
      const float r = ra[p + 3];
      const float gg = g * g;
      const float rr = r * r;
      const float gr = g * r;
      const int olo = (p - 10 < 0) ? 0 : p - 10;
      const int ohi = (p < 7) ? p : 7;
#pragma unroll
      for (int o = olo; o <= ohi; ++o) {
        const float wt = GW[p - o];
        acc5[0][o] = fmaf(wt, g, acc5[0][o]);
        acc5[1][o] = fmaf(wt, r, acc5[1][o]);
        acc5[2][o] = fmaf(wt, gg, acc5[2][o]);
        acc5[3][o] = fmaf(wt, rr, acc5[3][o]);
        acc5[4][o] = fmaf(wt, gr, acc5[4][o]);
      }
    }
    // Vectorized LDS writes: 2x float4 per quantity (rows 16B-aligned).
#pragma unroll
    for (int q = 0; q < 5; ++q) {
      *(float4*)&sh[q][row][xs + 0] =
          make_float4(acc5[q][0], acc5[q][1], acc5[q][2], acc5[q][3]);
      *(float4*)&sh[q][row][xs + 4] =
          make_float4(acc5[q][4], acc5[q][5], acc5[q][6], acc5[q][7]);
    }
  }
  __syncthreads();

  // ---- Phase 2: vertical 11-tap blur + SSIM. 64 cols x 4 groups x 5 rows.
  const int col = tid & 63;
  const int r0 = (tid >> 6) * 5;
  float hv[5][15];
#pragma unroll
  for (int q = 0; q < 5; ++q)
#pragma unroll
    for (int i = 0; i < 15; ++i) hv[q][i] = sh[q][r0 + i][col];

  const float C1 = 6.5025f, C2 = 58.5225f;
  float lsum = 0.f;
#pragma unroll
  for (int o = 0; o < 5; ++o) {
    float mu1 = 0.f, mu2 = 0.f, e1 = 0.f, e2 = 0.f, e12 = 0.f;
#pragma unroll
    for (int t = 0; t < 11; ++t) {
      const float wt = GW[t];
      mu1 = fmaf(wt, hv[0][o + t], mu1);
      mu2 = fmaf(wt, hv[1][o + t], mu2);
      e1 = fmaf(wt, hv[2][o + t], e1);
      e2 = fmaf(wt, hv[3][o + t], e2);
      e12 = fmaf(wt, hv[4][o + t], e12);
    }
    const float m12 = mu1 * mu2;
    const float m1s = mu1 * mu1;
    const float m2s = mu2 * mu2;
    const float num = (2.f * m12 + C1) * (2.f * (e12 - m12) + C2);
    const float den = (m1s + m2s + C1) * ((e1 - m1s) + (e2 - m2s) + C2);
    const int y = y0 + r0 + o;
    lsum += (y < IMH) ? __fdividef(num, den) : 0.f;
  }

  // Block reduction -> single device-scope atomicAdd(double) per block.
#pragma unroll
  for (int off = 32; off > 0; off >>= 1) lsum += __shfl_down(lsum, off, 64);
  __syncthreads();  // all sh reads done; safe to reuse LDS
  if ((tid & 63) == 0) ((float*)sh)[tid >> 6] = lsum;
  __syncthreads();
  if (tid == 0) {
    double bs = (double)((float*)sh)[0] + (double)((float*)sh)[1] +
                (double)((float*)sh)[2] + (double)((float*)sh)[3];
    atomicAdd(acc, bs);
  }
}

__global__ void ssim_init(double* __restrict__ acc) { *acc = 0.0; }

__global__ void ssim_final(const double* __restrict__ acc,
                           float* __restrict__ out) {
  const double npix = (double)NPLANES * (double)IMW * (double)IMH;
  out[0] = (float)(1.0 - *acc / npix);
}

extern "C" void kernel_launch(void* const* d_in, const int* in_sizes, int n_in,
                              void* d_out, int out_size, void* d_ws, size_t ws_size,
                              hipStream_t stream) {
  (void)in_sizes; (void)n_in; (void)out_size; (void)ws_size;
  const float* gen = (const float*)d_in[0];
  const float* ref = (const float*)d_in[1];
  double* acc = (double*)d_ws;  // 8 bytes; zeroed by ssim_init each call
  ssim_init<<<1, 1, 0, stream>>>(acc);
  ssim_main<<<NBLOCKS, 256, 0, stream>>>(gen, ref, acc);
  ssim_final<<<1, 1, 0, stream>>>(acc, (float*)d_out);
}

// Round 4
// 306.215 us; speedup vs baseline: 1.3323x; 1.3323x over previous
//
#include <hip/hip_runtime.h>

typedef float v2f __attribute__((ext_vector_type(2)));

#define TX 64
#define TY 20
#define PROWS (TY + 10)            // 30 rows of h-blurred data per tile
#define GRSTR 66                   // v2f stride: 132 words = 4 mod 32 -> uniform banks
#define SSTR 68                    // float stride: 272B rows, 16B-aligned, uniform banks
#define IMW 512
#define IMH 512
#define NPLANES 96                 // 32 * 3
#define NBX (IMW / TX)             // 8
#define NBY ((IMH + TY - 1) / TY)  // 26
#define NBLOCKS (NBX * NBY * NPLANES)  // 19968

// Gaussian(sigma=1.5, ws=11), double-computed, fp32-rounded (passed at absmax 0).
#define GW0 0.00102838f
#define GW1 0.00759877f
#define GW2 0.03600077f
#define GW3 0.10936069f
#define GW4 0.21300553f
#define GW5 0.26601172f

__device__ __forceinline__ void pkfma(v2f& acc, v2f a, v2f b) {
  // acc = a*b + acc, packed 2xfp32 in one issue slot.
  asm("v_pk_fma_f32 %0, %1, %2, %0" : "+v"(acc) : "v"(a), "v"(b));
}

__global__ __launch_bounds__(256, 4) void ssim_main(
    const float* __restrict__ gen, const float* __restrict__ ref,
    float* __restrict__ partial) {
  __shared__ __align__(16) v2f s_gr[PROWS][GRSTR];   // (g, r)   15,840 B
  __shared__ __align__(16) v2f s_qq[PROWS][GRSTR];   // (gg, rr) 15,840 B
  __shared__ __align__(16) float s_s[PROWS][SSTR];   // gr        8,160 B
  __shared__ float swsum[4];

  const float GW[11] = {GW0, GW1, GW2, GW3, GW4, GW5,
                        GW4, GW3, GW2, GW1, GW0};

  const int tid = threadIdx.x;
  const int bid = blockIdx.x;
  const int rem = bid % (NBX * NBY);
  const int plane = bid / (NBX * NBY);
  const int bx = rem % NBX;
  const int by = rem / NBX;
  const int x0 = bx * TX;
  const int y0 = by * TY;
  const float* gp = gen + (size_t)plane * (IMW * IMH);
  const float* rp = ref + (size_t)plane * (IMW * IMH);

  // ---- Phase 1: horizontal 11-tap blur, direct-from-global, packed streams.
  if (tid < PROWS * 8) {
    const int row = tid >> 3;
    const int xs = (tid & 7) * 8;
    const int gy = y0 - 5 + row;
    const int xbase = x0 + xs - 8;  // window cols [xbase, xbase+24)
    const float* grow = gp + (size_t)gy * IMW;
    const float* rrow = rp + (size_t)gy * IMW;

    v2f P[24];  // (g, r) transformed
    const bool interior = (bx >= 1) & (bx <= 6) & (by >= 1) & (by <= 24);
    if (interior) {
#pragma unroll
      for (int k = 0; k < 6; ++k) {
        const int c = xbase + 4 * k;
        const float4 g4 = *(const float4*)(grow + c);
        const float4 r4 = *(const float4*)(rrow + c);
        P[4 * k + 0] = (v2f){fmaf(0.5f, g4.x, 0.5f), fmaf(0.5f, r4.x, 0.5f)};
        P[4 * k + 1] = (v2f){fmaf(0.5f, g4.y, 0.5f), fmaf(0.5f, r4.y, 0.5f)};
        P[4 * k + 2] = (v2f){fmaf(0.5f, g4.z, 0.5f), fmaf(0.5f, r4.z, 0.5f)};
        P[4 * k + 3] = (v2f){fmaf(0.5f, g4.w, 0.5f), fmaf(0.5f, r4.w, 0.5f)};
      }
    } else {
      const bool rowok = (gy >= 0) && (gy < IMH);
#pragma unroll
      for (int k = 0; k < 6; ++k) {
        const int c = xbase + 4 * k;
        const bool ok = rowok && (c >= 0) && (c < IMW);
        float4 g4 = make_float4(-1.f, -1.f, -1.f, -1.f);
        float4 r4 = g4;  // transform maps -1 -> 0 (zero padding)
        if (ok) {
          g4 = *(const float4*)(grow + c);
          r4 = *(const float4*)(rrow + c);
        }
        P[4 * k + 0] = (v2f){fmaf(0.5f, g4.x, 0.5f), fmaf(0.5f, r4.x, 0.5f)};
        P[4 * k + 1] = (v2f){fmaf(0.5f, g4.y, 0.5f), fmaf(0.5f, r4.y, 0.5f)};
        P[4 * k + 2] = (v2f){fmaf(0.5f, g4.z, 0.5f), fmaf(0.5f, r4.z, 0.5f)};
        P[4 * k + 3] = (v2f){fmaf(0.5f, g4.w, 0.5f), fmaf(0.5f, r4.w, 0.5f)};
      }
    }

    v2f accP[8], accQ[8];
    float accS[8];
#pragma unroll
    for (int o = 0; o < 8; ++o) {
      accP[o] = (v2f){0.f, 0.f};
      accQ[o] = (v2f){0.f, 0.f};
      accS[o] = 0.f;
    }

#pragma unroll
    for (int p = 0; p < 18; ++p) {   // window position; col value = P[p+3]
      const v2f pv = P[p + 3];
      v2f qv;
      qv.x = pv.x * pv.x;
      qv.y = pv.y * pv.y;
      const float sv = pv.x * pv.y;
      const int olo = (p - 10 < 0) ? 0 : p - 10;
      const int ohi = (p < 7) ? p : 7;
#pragma unroll
      for (int o = olo; o <= ohi; ++o) {
        const float wt = GW[p - o];
        const v2f wv = (v2f){wt, wt};
        pkfma(accP[o], wv, pv);
        pkfma(accQ[o], wv, qv);
        accS[o] = fmaf(wt, sv, accS[o]);
      }
    }

    // Vectorized LDS writes (all 16B-aligned).
    float4* wp = (float4*)&s_gr[row][xs];
    wp[0] = make_float4(accP[0].x, accP[0].y, accP[1].x, accP[1].y);
    wp[1] = make_float4(accP[2].x, accP[2].y, accP[3].x, accP[3].y);
    wp[2] = make_float4(accP[4].x, accP[4].y, accP[5].x, accP[5].y);
    wp[3] = make_float4(accP[6].x, accP[6].y, accP[7].x, accP[7].y);
    float4* wq = (float4*)&s_qq[row][xs];
    wq[0] = make_float4(accQ[0].x, accQ[0].y, accQ[1].x, accQ[1].y);
    wq[1] = make_float4(accQ[2].x, accQ[2].y, accQ[3].x, accQ[3].y);
    wq[2] = make_float4(accQ[4].x, accQ[4].y, accQ[5].x, accQ[5].y);
    wq[3] = make_float4(accQ[6].x, accQ[6].y, accQ[7].x, accQ[7].y);
    float4* ws = (float4*)&s_s[row][xs];
    ws[0] = make_float4(accS[0], accS[1], accS[2], accS[3]);
    ws[1] = make_float4(accS[4], accS[5], accS[6], accS[7]);
  }
  __syncthreads();

  // ---- Phase 2: vertical 11-tap blur + SSIM. 64 cols x 4 groups x 5 rows.
  const int col = tid & 63;
  const int r0 = (tid >> 6) * 5;
  v2f hp[15], hq[15];
  float hs[15];
#pragma unroll
  for (int i = 0; i < 15; ++i) {
    hp[i] = s_gr[r0 + i][col];
    hq[i] = s_qq[r0 + i][col];
    hs[i] = s_s[r0 + i][col];
  }

  const float C1 = 6.5025f, C2 = 58.5225f;
  float lsum = 0.f;
#pragma unroll
  for (int o = 0; o < 5; ++o) {
    v2f mu = (v2f){0.f, 0.f};
    v2f ee = (v2f){0.f, 0.f};
    float e12 = 0.f;
#pragma unroll
    for (int t = 0; t < 11; ++t) {
      const float wt = GW[t];
      const v2f wv = (v2f){wt, wt};
      pkfma(mu, wv, hp[o + t]);
      pkfma(ee, wv, hq[o + t]);
      e12 = fmaf(wt, hs[o + t], e12);
    }
    const float mu1 = mu.x, mu2 = mu.y, e1 = ee.x, e2 = ee.y;
    const float m12 = mu1 * mu2;
    const float m1s = mu1 * mu1;
    const float m2s = mu2 * mu2;
    const float num = (2.f * m12 + C1) * (2.f * (e12 - m12) + C2);
    const float den = (m1s + m2s + C1) * ((e1 - m1s) + (e2 - m2s) + C2);
    const int y = y0 + r0 + o;
    lsum += (y < IMH) ? __fdividef(num, den) : 0.f;
  }

  // Block reduction -> deterministic per-block partial.
#pragma unroll
  for (int off = 32; off > 0; off >>= 1) lsum += __shfl_down(lsum, off, 64);
  if ((tid & 63) == 0) swsum[tid >> 6] = lsum;
  __syncthreads();
  if (tid == 0) partial[bid] = swsum[0] + swsum[1] + swsum[2] + swsum[3];
}

__global__ void ssim_reduce(const float* __restrict__ partial,
                            float* __restrict__ out) {
  const int nv = NBLOCKS / 4;  // 4992 float4
  double s = 0.0;
  for (int i = threadIdx.x; i < nv; i += 256) {
    float4 v = ((const float4*)partial)[i];
    s += (double)v.x + (double)v.y + (double)v.z + (double)v.w;
  }
#pragma unroll
  for (int off = 32; off > 0; off >>= 1) s += __shfl_down(s, off, 64);
  __shared__ double sd[4];
  if ((threadIdx.x & 63) == 0) sd[threadIdx.x >> 6] = s;
  __syncthreads();
  if (threadIdx.x == 0) {
    double npix = (double)NPLANES * (double)IMW * (double)IMH;
    out[0] = (float)(1.0 - (sd[0] + sd[1] + sd[2] + sd[3]) / npix);
  }
}

extern "C" void kernel_launch(void* const* d_in, const int* in_sizes, int n_in,
                              void* d_out, int out_size, void* d_ws, size_t ws_size,
                              hipStream_t stream) {
  (void)in_sizes; (void)n_in; (void)out_size; (void)ws_size;
  const float* gen = (const float*)d_in[0];
  const float* ref = (const float*)d_in[1];
  float* partial = (float*)d_ws;  // NBLOCKS floats; every slot written each call
  ssim_main<<<NBLOCKS, 256, 0, stream>>>(gen, ref, partial);
  ssim_reduce<<<1, 256, 0, stream>>>(partial, (float*)d_out);
}

// Round 5
// 295.992 us; speedup vs baseline: 1.3783x; 1.0345x over previous
//
#include <hip/hip_runtime.h>

typedef float v2f __attribute__((ext_vector_type(2)));

#define TX 64
#define TY 20
#define PROWS (TY + 10)            // 30 rows of h-blurred data per tile
#define HSTR 67                    // scalar stride: 67%32=3 -> 2-way max (free)
#define IMW 512
#define IMH 512
#define NPLANES 96                 // 32 * 3
#define NBX (IMW / TX)             // 8
#define NBY ((IMH + TY - 1) / TY)  // 26
#define NBLOCKS (NBX * NBY * NPLANES)  // 19968

// Gaussian(sigma=1.5, ws=11), double-computed, fp32-rounded (passed at absmax 0).
#define GW0 0.00102838f
#define GW1 0.00759877f
#define GW2 0.03600077f
#define GW3 0.10936069f
#define GW4 0.21300553f
#define GW5 0.26601172f

__device__ __forceinline__ void pkfma(v2f& acc, v2f a, v2f b) {
  asm("v_pk_fma_f32 %0, %1, %2, %0" : "+v"(acc) : "v"(a), "v"(b));
}
__device__ __forceinline__ v2f pkmul(v2f a, v2f b) {
  v2f d;
  asm("v_pk_mul_f32 %0, %1, %2" : "=v"(d) : "v"(a), "v"(b));
  return d;
}

__global__ __launch_bounds__(256, 4) void ssim_main(
    const float* __restrict__ gen, const float* __restrict__ ref,
    float* __restrict__ partial) {
  // 5 scalar arrays, stride 67: phase-1 writes (3row+8seg) -> 2 lanes/bank,
  // phase-2 reads (col mod 32) -> 2 lanes/bank. Both free per m136.
  __shared__ float s_q[5][PROWS][HSTR];  // 40,200 B -> 4 blocks/CU
  __shared__ float swsum[4];

  const float GW[11] = {GW0, GW1, GW2, GW3, GW4, GW5,
                        GW4, GW3, GW2, GW1, GW0};

  const int tid = threadIdx.x;
  const int bid = blockIdx.x;
  const int rem = bid % (NBX * NBY);
  const int plane = bid / (NBX * NBY);
  const int bx = rem % NBX;
  const int by = rem / NBX;
  const int x0 = bx * TX;
  const int y0 = by * TY;
  const float* gp = gen + (size_t)plane * (IMW * IMH);
  const float* rp = ref + (size_t)plane * (IMW * IMH);

  // ---- Phase 1: horizontal 11-tap blur, direct-from-global, packed regs.
  // 240 threads: (row 0..29) x (8 runs of 8 outputs). Window = 24 floats
  // loaded as 6 aligned float4 (each fully in or fully out of the image).
  if (tid < PROWS * 8) {
    const int row = tid >> 3;
    const int xs = (tid & 7) * 8;
    const int gy = y0 - 5 + row;
    const int xbase = x0 + xs - 8;  // window cols [xbase, xbase+24)
    const float* grow = gp + (size_t)gy * IMW;
    const float* rrow = rp + (size_t)gy * IMW;

    v2f P[24];  // (g, r) transformed, packed per column
    const bool interior = (bx >= 1) & (bx <= 6) & (by >= 1) & (by <= 24);
    if (interior) {
#pragma unroll
      for (int k = 0; k < 6; ++k) {
        const int c = xbase + 4 * k;
        const float4 g4 = *(const float4*)(grow + c);
        const float4 r4 = *(const float4*)(rrow + c);
        P[4 * k + 0] = (v2f){fmaf(0.5f, g4.x, 0.5f), fmaf(0.5f, r4.x, 0.5f)};
        P[4 * k + 1] = (v2f){fmaf(0.5f, g4.y, 0.5f), fmaf(0.5f, r4.y, 0.5f)};
        P[4 * k + 2] = (v2f){fmaf(0.5f, g4.z, 0.5f), fmaf(0.5f, r4.z, 0.5f)};
        P[4 * k + 3] = (v2f){fmaf(0.5f, g4.w, 0.5f), fmaf(0.5f, r4.w, 0.5f)};
      }
    } else {
      const bool rowok = (gy >= 0) && (gy < IMH);
#pragma unroll
      for (int k = 0; k < 6; ++k) {
        const int c = xbase + 4 * k;
        const bool ok = rowok && (c >= 0) && (c < IMW);
        float4 g4 = make_float4(-1.f, -1.f, -1.f, -1.f);
        float4 r4 = g4;  // transform maps -1 -> 0 (matches zero padding)
        if (ok) {
          g4 = *(const float4*)(grow + c);
          r4 = *(const float4*)(rrow + c);
        }
        P[4 * k + 0] = (v2f){fmaf(0.5f, g4.x, 0.5f), fmaf(0.5f, r4.x, 0.5f)};
        P[4 * k + 1] = (v2f){fmaf(0.5f, g4.y, 0.5f), fmaf(0.5f, r4.y, 0.5f)};
        P[4 * k + 2] = (v2f){fmaf(0.5f, g4.z, 0.5f), fmaf(0.5f, r4.z, 0.5f)};
        P[4 * k + 3] = (v2f){fmaf(0.5f, g4.w, 0.5f), fmaf(0.5f, r4.w, 0.5f)};
      }
    }

    v2f accP[8], accQ[8];
    float accS[8];
#pragma unroll
    for (int o = 0; o < 8; ++o) {
      accP[o] = (v2f){0.f, 0.f};
      accQ[o] = (v2f){0.f, 0.f};
      accS[o] = 0.f;
    }

#pragma unroll
    for (int p = 0; p < 18; ++p) {   // window position; col value = P[p+3]
      const v2f pv = P[p + 3];
      const v2f qv = pkmul(pv, pv);
      const float sv = pv.x * pv.y;
      const int olo = (p - 10 < 0) ? 0 : p - 10;
      const int ohi = (p < 7) ? p : 7;
#pragma unroll
      for (int o = olo; o <= ohi; ++o) {
        const float wt = GW[p - o];
        const v2f wv = (v2f){wt, wt};
        pkfma(accP[o], wv, pv);
        pkfma(accQ[o], wv, qv);
        accS[o] = fmaf(wt, sv, accS[o]);
      }
    }

    // Component-wise scalar stores; compiler pairs them into ds_write2_b32.
#pragma unroll
    for (int o = 0; o < 8; ++o) s_q[0][row][xs + o] = accP[o].x;
#pragma unroll
    for (int o = 0; o < 8; ++o) s_q[1][row][xs + o] = accP[o].y;
#pragma unroll
    for (int o = 0; o < 8; ++o) s_q[2][row][xs + o] = accQ[o].x;
#pragma unroll
    for (int o = 0; o < 8; ++o) s_q[3][row][xs + o] = accQ[o].y;
#pragma unroll
    for (int o = 0; o < 8; ++o) s_q[4][row][xs + o] = accS[o];
  }
  __syncthreads();

  // ---- Phase 2: vertical 11-tap blur + SSIM. 64 cols x 4 groups x 5 rows.
  const int col = tid & 63;
  const int r0 = (tid >> 6) * 5;
  v2f hp[15], hq[15];
  float hs[15];
#pragma unroll
  for (int i = 0; i < 15; ++i) {
    hp[i] = (v2f){s_q[0][r0 + i][col], s_q[1][r0 + i][col]};
    hq[i] = (v2f){s_q[2][r0 + i][col], s_q[3][r0 + i][col]};
    hs[i] = s_q[4][r0 + i][col];
  }

  const float C1 = 6.5025f, C2 = 58.5225f;
  float lsum = 0.f;
#pragma unroll
  for (int o = 0; o < 5; ++o) {
    v2f mu = (v2f){0.f, 0.f};
    v2f ee = (v2f){0.f, 0.f};
    float e12 = 0.f;
#pragma unroll
    for (int t = 0; t < 11; ++t) {
      const float wt = GW[t];
      const v2f wv = (v2f){wt, wt};
      pkfma(mu, wv, hp[o + t]);
      pkfma(ee, wv, hq[o + t]);
      e12 = fmaf(wt, hs[o + t], e12);
    }
    const float mu1 = mu.x, mu2 = mu.y, e1 = ee.x, e2 = ee.y;
    const float m12 = mu1 * mu2;
    const float m1s = mu1 * mu1;
    const float m2s = mu2 * mu2;
    const float num = (2.f * m12 + C1) * (2.f * (e12 - m12) + C2);
    const float den = (m1s + m2s + C1) * ((e1 - m1s) + (e2 - m2s) + C2);
    const int y = y0 + r0 + o;
    lsum += (y < IMH) ? __fdividef(num, den) : 0.f;
  }

  // Block reduction -> deterministic per-block partial.
#pragma unroll
  for (int off = 32; off > 0; off >>= 1) lsum += __shfl_down(lsum, off, 64);
  if ((tid & 63) == 0) swsum[tid >> 6] = lsum;
  __syncthreads();
  if (tid == 0) partial[bid] = swsum[0] + swsum[1] + swsum[2] + swsum[3];
}

__global__ void ssim_reduce(const float* __restrict__ partial,
                            float* __restrict__ out) {
  const int nv = NBLOCKS / 4;  // 4992 float4
  double s = 0.0;
  for (int i = threadIdx.x; i < nv; i += 256) {
    float4 v = ((const float4*)partial)[i];
    s += (double)v.x + (double)v.y + (double)v.z + (double)v.w;
  }
#pragma unroll
  for (int off = 32; off > 0; off >>= 1) s += __shfl_down(s, off, 64);
  __shared__ double sd[4];
  if ((threadIdx.x & 63) == 0) sd[threadIdx.x >> 6] = s;
  __syncthreads();
  if (threadIdx.x == 0) {
    double npix = (double)NPLANES * (double)IMW * (double)IMH;
    out[0] = (float)(1.0 - (sd[0] + sd[1] + sd[2] + sd[3]) / npix);
  }
}

extern "C" void kernel_launch(void* const* d_in, const int* in_sizes, int n_in,
                              void* d_out, int out_size, void* d_ws, size_t ws_size,
                              hipStream_t stream) {
  (void)in_sizes; (void)n_in; (void)out_size; (void)ws_size;
  const float* gen = (const float*)d_in[0];
  const float* ref = (const float*)d_in[1];
  float* partial = (float*)d_ws;  // NBLOCKS floats; every slot written each call
  ssim_main<<<NBLOCKS, 256, 0, stream>>>(gen, ref, partial);
  ssim_reduce<<<1, 256, 0, stream>>>(partial, (float*)d_out);
}